// Round 1
// baseline (895.672 us; speedup 1.0000x reference)
//
#include <hip/hip_runtime.h>
#include <math.h>

#define FF 512
#define EE 32
#define FXS 36   // padded LDS row stride in floats (144B, 16B-aligned)

__device__ __forceinline__ float4 f4fma(float4 a, float4 b, float4 c) {
    return make_float4(fmaf(a.x, b.x, c.x), fmaf(a.y, b.y, c.y),
                       fmaf(a.z, b.z, c.z), fmaf(a.w, b.w, c.w));
}

template <bool TWO>
__device__ __forceinline__ void score_passes(const float* __restrict__ fx,
                                             float* __restrict__ Zs,
                                             float* __restrict__ ws,
                                             int cnt, int tid, int lane) {
    const float scale = 0.17677669529663687f;  // 1/sqrt(32)
    float4 k1[8], k2[8];
    const bool a1 = (tid < cnt);
    const bool a2 = TWO && (tid + 256 < cnt);
#pragma unroll
    for (int m = 0; m < 8; ++m) {
        k1[m] = make_float4(0.f, 0.f, 0.f, 0.f);
        if (TWO) k2[m] = make_float4(0.f, 0.f, 0.f, 0.f);
    }
    if (a1) {
#pragma unroll
        for (int m = 0; m < 8; ++m) k1[m] = *(const float4*)(fx + tid * FXS + 4 * m);
    }
    if (TWO && a2) {
#pragma unroll
        for (int m = 0; m < 8; ++m) k2[m] = *(const float4*)(fx + (tid + 256) * FXS + 4 * m);
    }

    // ---- pass 1: Z_q = sum_k exp(scale * dot(q,k)) ----
    for (int q = 0; q < cnt; ++q) {
        const float* qr = fx + q * FXS;
        float4 A1 = make_float4(0.f, 0.f, 0.f, 0.f);
        float4 A2 = make_float4(0.f, 0.f, 0.f, 0.f);
#pragma unroll
        for (int m = 0; m < 8; ++m) {
            float4 qv = *(const float4*)(qr + 4 * m);
            A1 = f4fma(qv, k1[m], A1);
            if (TWO) A2 = f4fma(qv, k2[m], A2);
        }
        float d1 = (A1.x + A1.y) + (A1.z + A1.w);
        float v = a1 ? __expf(d1 * scale) : 0.f;
        if (TWO) {
            float d2 = (A2.x + A2.y) + (A2.z + A2.w);
            v += a2 ? __expf(d2 * scale) : 0.f;
        }
#pragma unroll
        for (int o = 32; o; o >>= 1) v += __shfl_xor(v, o);
        if (lane == 0) atomicAdd(&Zs[q], v);
    }
    __syncthreads();
    for (int q = tid; q < cnt; q += 256) Zs[q] = 1.f / fmaxf(Zs[q], 1e-9f);
    __syncthreads();

    // ---- pass 2: w_k = sum_q exp(scale * dot(q,k)) / Z_q ----
    float w1 = 0.f, w2 = 0.f;
    for (int q = 0; q < cnt; ++q) {
        const float* qr = fx + q * FXS;
        float4 A1 = make_float4(0.f, 0.f, 0.f, 0.f);
        float4 A2 = make_float4(0.f, 0.f, 0.f, 0.f);
#pragma unroll
        for (int m = 0; m < 8; ++m) {
            float4 qv = *(const float4*)(qr + 4 * m);
            A1 = f4fma(qv, k1[m], A1);
            if (TWO) A2 = f4fma(qv, k2[m], A2);
        }
        float iz = Zs[q];
        float d1 = (A1.x + A1.y) + (A1.z + A1.w);
        w1 = fmaf(__expf(d1 * scale), iz, w1);
        if (TWO) {
            float d2 = (A2.x + A2.y) + (A2.z + A2.w);
            w2 = fmaf(__expf(d2 * scale), iz, w2);
        }
    }
    if (a1) ws[tid] = w1;
    if (TWO && a2) ws[tid + 256] = w2;
    __syncthreads();
}

extern "C" __global__ void __launch_bounds__(256, 2)
model_kernel(const float* __restrict__ X, const float* __restrict__ Xi,
             const float* __restrict__ I, const float* __restrict__ S,
             const float* __restrict__ xi_w, const float* __restrict__ xi_b,
             const float* __restrict__ xs_w, const float* __restrict__ xs_b,
             float* __restrict__ out) {
    const int n = blockIdx.x;
    const int tid = threadIdx.x;
    const int lane = tid & 63;
    const int wv = tid >> 6;

    __shared__ __align__(16) float fx[FF * FXS];   // 73728 B
    __shared__ unsigned short lst[FF];             // 1024 B
    __shared__ float Zs[FF];                       // 2048 B (becomes invZ)
    __shared__ float ws[FF];                       // 2048 B
    __shared__ __align__(16) float idxb[EE];       // 128 B
    __shared__ float pf[8][EE];                    // 1024 B
    __shared__ float fxs_sh[EE];                   // 128 B
    __shared__ int sh_idx;
    __shared__ int wbase[4];

    const float* Srow = S + (size_t)n * FF;
    const float* Irow = I + (size_t)n * FF;
    const float* Xrow = X + (size_t)n * FF;

    // one-hot index scan + zero Z
    for (int f = tid; f < FF; f += 256)
        if (Irow[f] > 0.5f) sh_idx = f;
    for (int q = tid; q < FF; q += 256) Zs[q] = 0.f;

    // compact active feature list (order-preserving)
    int base = 0;
    for (int r = 0; r < 2; ++r) {
        int f = r * 256 + tid;
        bool act = Srow[f] > 0.f;
        unsigned long long m = __ballot(act);
        int nb = __popcll(m & ((1ull << lane) - 1ull));
        int wc = __popcll(m);
        if (lane == 0) wbase[wv] = wc;
        __syncthreads();
        int off = base;
        for (int i = 0; i < wv; ++i) off += wbase[i];
        if (act) lst[off + nb] = (unsigned short)f;
        base += wbase[0] + wbase[1] + wbase[2] + wbase[3];
        __syncthreads();
    }
    const int cnt = base;            // block-uniform
    const int idx = sh_idx;
    if (tid < EE) idxb[tid] = xs_b[idx * EE + tid];
    __syncthreads();

    // build FX (compacted active rows) into LDS
    for (int jb = 0; jb < cnt; jb += 32) {
        int j = jb + (tid >> 3);
        int e4 = (tid & 7) * 4;
        if (j < cnt) {
            int f = lst[j];
            float xv = Xrow[f];
            float4 w4 = *(const float4*)(xs_w + f * EE + e4);
            float4 b4 = *(const float4*)(xs_b + f * EE + e4);
            float4 i4 = *(const float4*)(idxb + e4);
            float4 r;
            r.x = fmaf(xv, w4.x, b4.x + i4.x);
            r.y = fmaf(xv, w4.y, b4.y + i4.y);
            r.z = fmaf(xv, w4.z, b4.z + i4.z);
            r.w = fmaf(xv, w4.w, b4.w + i4.w);
            *(float4*)(fx + j * FXS + e4) = r;
        }
    }
    __syncthreads();

    if (cnt <= 256)
        score_passes<false>(fx, Zs, ws, cnt, tid, lane);
    else
        score_passes<true>(fx, Zs, ws, cnt, tid, lane);

    // Fxs[e] = (sum_k w_k * fx[k][e]) / cnt   (8-way split over k)
    {
        int e = tid & 31, g = tid >> 5;
        float acc = 0.f;
        for (int j = g; j < cnt; j += 8) acc += ws[j] * fx[j * FXS + e];
        pf[g][e] = acc;
    }
    __syncthreads();
    if (tid < EE) {
        float s = 0.f;
#pragma unroll
        for (int g = 0; g < 8; ++g) s += pf[g][tid];
        fxs_sh[tid] = s / (float)cnt;
    }
    __syncthreads();
    if (tid < EE) {
        float fv = fxs_sh[tid];
        pf[0][tid] = xi_w[idx * EE + tid] * fv;
        pf[1][tid] = xi_b[idx * EE + tid] * fv;
    }
    __syncthreads();
    if (tid == 0) {
        float a = 0.f, b = 0.f;
#pragma unroll
        for (int e = 0; e < EE; ++e) { a += pf[0][e]; b += pf[1][e]; }
        (void)b;  // cancels: out = Xi*a + b - (b + softplus(a))
        float xiv = Xi[n];
        float mm = fmaxf(a, 0.f);
        float sp = mm + logf(__expf(a - mm) + __expf(-mm));
        out[n] = xiv * a - sp;
    }
}

extern "C" void kernel_launch(void* const* d_in, const int* in_sizes, int n_in,
                              void* d_out, int out_size, void* d_ws, size_t ws_size,
                              hipStream_t stream) {
    const float* X    = (const float*)d_in[0];
    const float* Xi   = (const float*)d_in[1];
    const float* I    = (const float*)d_in[2];
    const float* S    = (const float*)d_in[3];
    const float* xi_w = (const float*)d_in[4];
    const float* xi_b = (const float*)d_in[5];
    const float* xs_w = (const float*)d_in[6];
    const float* xs_b = (const float*)d_in[7];
    float* out = (float*)d_out;
    const int N = in_sizes[1];  // Xi is [N]
    hipLaunchKernelGGL(model_kernel, dim3(N), dim3(256), 0, stream,
                       X, Xi, I, S, xi_w, xi_b, xs_w, xs_b, out);
}

// Round 2
// 160.161 us; speedup vs baseline: 5.5923x; 5.5923x over previous
//
#include <hip/hip_runtime.h>
#include <math.h>

#define FF 512
#define EE 32
#define RS 40   // LDS row stride in bf16 elements (80 B: 2-way bank alias = free)

typedef __attribute__((ext_vector_type(8))) short bf16x8;
typedef __attribute__((ext_vector_type(4))) float f32x4;

__device__ __forceinline__ unsigned short f2bf(float x) {
    unsigned int u = __float_as_uint(x);
    return (unsigned short)((u + 0x7fffu + ((u >> 16) & 1u)) >> 16);
}
__device__ __forceinline__ float bf2f(unsigned short h) {
    return __uint_as_float(((unsigned int)h) << 16);
}

extern "C" __global__ void __launch_bounds__(256, 3)
model_kernel(const float* __restrict__ X, const float* __restrict__ Xi,
             const float* __restrict__ I, const float* __restrict__ S,
             const float* __restrict__ xi_w, const float* __restrict__ xi_b,
             const float* __restrict__ xs_w, const float* __restrict__ xs_b,
             float* __restrict__ out) {
    const int n = blockIdx.x;
    const int tid = threadIdx.x;
    const int lane = tid & 63;
    const int wv = tid >> 6;
    const int l15 = lane & 15;
    const int grp = lane >> 4;
    const float scale = 0.17677669529663687f;  // 1/sqrt(32)

    __shared__ __align__(16) unsigned short fxb[FF * RS];  // 40960 B bf16
    __shared__ unsigned short lst[FF];                     // 1024 B
    __shared__ float Zs[FF];                               // 2048 B -> invZ
    __shared__ float ws[FF];                               // 2048 B
    __shared__ __align__(16) float idxb[EE];
    __shared__ float pf[8][EE];
    __shared__ float fxs_sh[EE];
    __shared__ int sh_idx;
    __shared__ int wbase[4];

    const float* Srow = S + (size_t)n * FF;
    const float* Irow = I + (size_t)n * FF;
    const float* Xrow = X + (size_t)n * FF;

    // one-hot index scan
    for (int f = tid; f < FF; f += 256)
        if (Irow[f] > 0.5f) sh_idx = f;

    // compact active feature list (order-preserving)
    int base = 0;
    for (int r = 0; r < 2; ++r) {
        int f = r * 256 + tid;
        bool act = Srow[f] > 0.f;
        unsigned long long m = __ballot(act);
        int nb = __popcll(m & ((1ull << lane) - 1ull));
        int wc = __popcll(m);
        if (lane == 0) wbase[wv] = wc;
        __syncthreads();
        int off = base;
        for (int i = 0; i < wv; ++i) off += wbase[i];
        if (act) lst[off + nb] = (unsigned short)f;
        base += wbase[0] + wbase[1] + wbase[2] + wbase[3];
        __syncthreads();
    }
    const int cnt = base;           // block-uniform, >=1
    const int nt = (cnt + 15) >> 4; // 16x16 tiles per side
    const int ntp16 = nt * 16;
    const int idx = sh_idx;
    if (tid < EE) idxb[tid] = xs_b[idx * EE + tid];
    __syncthreads();

    // ---- build FX (compacted, bf16) into LDS; zero-pad to tile boundary ----
    for (int jb = 0; jb < ntp16; jb += 32) {
        int j = jb + (tid >> 3);
        int e4 = (tid & 7) * 4;
        if (j < ntp16) {
            unsigned short h0 = 0, h1 = 0, h2 = 0, h3 = 0;
            if (j < cnt) {
                int f = lst[j];
                float xv = Xrow[f];
                float4 w4 = *(const float4*)(xs_w + f * EE + e4);
                float4 b4 = *(const float4*)(xs_b + f * EE + e4);
                float4 i4 = *(const float4*)(idxb + e4);
                h0 = f2bf(fmaf(xv, w4.x, b4.x + i4.x));
                h1 = f2bf(fmaf(xv, w4.y, b4.y + i4.y));
                h2 = f2bf(fmaf(xv, w4.z, b4.z + i4.z));
                h3 = f2bf(fmaf(xv, w4.w, b4.w + i4.w));
            }
            ushort4 pk = make_ushort4(h0, h1, h2, h3);
            *(ushort4*)(fxb + j * RS + e4) = pk;
        }
    }
    __syncthreads();

    // ---- pass 1: Z_q via MFMA over 16x16 score tiles ----
    for (int i = wv; i < nt; i += 4) {
        bf16x8 afrag = *(const bf16x8*)(fxb + (i * 16 + l15) * RS + grp * 8);
        float zacc0 = 0.f, zacc1 = 0.f, zacc2 = 0.f, zacc3 = 0.f;
        for (int j = 0; j < nt; ++j) {
            bf16x8 bfrag = *(const bf16x8*)(fxb + (j * 16 + l15) * RS + grp * 8);
            f32x4 d = {0.f, 0.f, 0.f, 0.f};
            d = __builtin_amdgcn_mfma_f32_16x16x32_bf16(afrag, bfrag, d, 0, 0, 0);
            bool cv = (j * 16 + l15) < cnt;
            zacc0 += cv ? __expf(d[0] * scale) : 0.f;
            zacc1 += cv ? __expf(d[1] * scale) : 0.f;
            zacc2 += cv ? __expf(d[2] * scale) : 0.f;
            zacc3 += cv ? __expf(d[3] * scale) : 0.f;
        }
#pragma unroll
        for (int o = 1; o < 16; o <<= 1) {
            zacc0 += __shfl_xor(zacc0, o);
            zacc1 += __shfl_xor(zacc1, o);
            zacc2 += __shfl_xor(zacc2, o);
            zacc3 += __shfl_xor(zacc3, o);
        }
        if (l15 == 0) {
            int q = i * 16 + grp * 4;
            Zs[q + 0] = zacc0; Zs[q + 1] = zacc1;
            Zs[q + 2] = zacc2; Zs[q + 3] = zacc3;
        }
    }
    __syncthreads();
    for (int q = tid; q < ntp16; q += 256)
        Zs[q] = (q < cnt) ? 1.f / fmaxf(Zs[q], 1e-9f) : 0.f;
    __syncthreads();

    // ---- pass 2: w_k = sum_q exp(s_qk) * invZ_q ----
    for (int j = wv; j < nt; j += 4) {
        bf16x8 bfrag = *(const bf16x8*)(fxb + (j * 16 + l15) * RS + grp * 8);
        float wacc = 0.f;
        for (int i = 0; i < nt; ++i) {
            bf16x8 afrag = *(const bf16x8*)(fxb + (i * 16 + l15) * RS + grp * 8);
            f32x4 d = {0.f, 0.f, 0.f, 0.f};
            d = __builtin_amdgcn_mfma_f32_16x16x32_bf16(afrag, bfrag, d, 0, 0, 0);
            int qb = i * 16 + grp * 4;
            wacc = fmaf(__expf(d[0] * scale), Zs[qb + 0], wacc);
            wacc = fmaf(__expf(d[1] * scale), Zs[qb + 1], wacc);
            wacc = fmaf(__expf(d[2] * scale), Zs[qb + 2], wacc);
            wacc = fmaf(__expf(d[3] * scale), Zs[qb + 3], wacc);
        }
        wacc += __shfl_xor(wacc, 16);
        wacc += __shfl_xor(wacc, 32);
        if (lane < 16) ws[j * 16 + lane] = wacc;
    }
    __syncthreads();

    // ---- Fxs[e] = (sum_k w_k * fx[k][e]) / cnt ----
    {
        int e = tid & 31, g = tid >> 5;
        float acc = 0.f;
        for (int k = g; k < cnt; k += 8)
            acc += ws[k] * bf2f(fxb[k * RS + e]);
        pf[g][e] = acc;
    }
    __syncthreads();
    if (tid < EE) {
        float s = 0.f;
#pragma unroll
        for (int g = 0; g < 8; ++g) s += pf[g][tid];
        fxs_sh[tid] = s / (float)cnt;
    }
    __syncthreads();
    if (tid < EE) {
        float fv = fxs_sh[tid];
        pf[0][tid] = xi_w[idx * EE + tid] * fv;
    }
    __syncthreads();
    if (tid == 0) {
        float a = 0.f;
#pragma unroll
        for (int e = 0; e < EE; ++e) a += pf[0][e];
        float xiv = Xi[n];
        float mm = fmaxf(a, 0.f);
        float sp = mm + logf(__expf(a - mm) + __expf(-mm));
        out[n] = xiv * a - sp;  // xi*a - softplus(a); b-terms cancel
    }
}

extern "C" void kernel_launch(void* const* d_in, const int* in_sizes, int n_in,
                              void* d_out, int out_size, void* d_ws, size_t ws_size,
                              hipStream_t stream) {
    const float* X    = (const float*)d_in[0];
    const float* Xi   = (const float*)d_in[1];
    const float* I    = (const float*)d_in[2];
    const float* S    = (const float*)d_in[3];
    const float* xi_w = (const float*)d_in[4];
    const float* xi_b = (const float*)d_in[5];
    const float* xs_w = (const float*)d_in[6];
    const float* xs_b = (const float*)d_in[7];
    float* out = (float*)d_out;
    const int N = in_sizes[1];  // Xi is [N]
    hipLaunchKernelGGL(model_kernel, dim3(N), dim3(256), 0, stream,
                       X, Xi, I, S, xi_w, xi_b, xs_w, xs_b, out);
}

// Round 3
// 137.666 us; speedup vs baseline: 6.5061x; 1.1634x over previous
//
#include <hip/hip_runtime.h>
#include <math.h>

#define FF 512
#define EE 32
#define RS 40   // LDS row stride in bf16 elements (80 B: 2-way bank alias = free)

typedef __attribute__((ext_vector_type(8))) short bf16x8;
typedef __attribute__((ext_vector_type(4))) float f32x4;

// sqrt(1/sqrt(32) * log2(e)) — folded into staged FX so MFMA output is the exp2 arg
#define SFOLD 0.5050092f

__device__ __forceinline__ unsigned short f2bf(float x) {
    unsigned int u = __float_as_uint(x);
    return (unsigned short)((u + 0x7fffu + ((u >> 16) & 1u)) >> 16);
}
__device__ __forceinline__ float bf2f(unsigned short h) {
    return __uint_as_float(((unsigned int)h) << 16);
}

extern "C" __global__ void __launch_bounds__(256, 3)
model_kernel(const float* __restrict__ X, const float* __restrict__ Xi,
             const float* __restrict__ I, const float* __restrict__ S,
             const float* __restrict__ xi_w, const float* __restrict__ xi_b,
             const float* __restrict__ xs_w, const float* __restrict__ xs_b,
             float* __restrict__ out) {
    const int n = blockIdx.x;
    const int tid = threadIdx.x;
    const int lane = tid & 63;
    const int wv = tid >> 6;
    const int l15 = lane & 15;
    const int grp = lane >> 4;

    __shared__ __align__(16) unsigned short fxb[FF * RS];  // 40960 B bf16 (scaled FX)
    __shared__ unsigned short lst[FF];                     // 1024 B
    __shared__ __align__(16) float Zs[FF];                 // 2048 B -> invZ
    __shared__ float ws[FF];                               // 2048 B
    __shared__ __align__(16) float idxb[EE];
    __shared__ float pf[8][EE];
    __shared__ float fxs_sh[EE];
    __shared__ int sh_idx;
    __shared__ int wbase[4];

    const float* Srow = S + (size_t)n * FF;
    const float* Irow = I + (size_t)n * FF;
    const float* Xrow = X + (size_t)n * FF;

    // one-hot index scan
    for (int f = tid; f < FF; f += 256)
        if (Irow[f] > 0.5f) sh_idx = f;

    // compact active feature list (order-preserving)
    int base = 0;
    for (int r = 0; r < 2; ++r) {
        int f = r * 256 + tid;
        bool act = Srow[f] > 0.f;
        unsigned long long m = __ballot(act);
        int nb = __popcll(m & ((1ull << lane) - 1ull));
        int wc = __popcll(m);
        if (lane == 0) wbase[wv] = wc;
        __syncthreads();
        int off = base;
        for (int i = 0; i < wv; ++i) off += wbase[i];
        if (act) lst[off + nb] = (unsigned short)f;
        base += wbase[0] + wbase[1] + wbase[2] + wbase[3];
        __syncthreads();
    }
    const int cnt = base;           // block-uniform, >=1
    const int nt = (cnt + 15) >> 4; // 16x16 tiles per side
    const int ntp16 = nt * 16;
    const int idx = sh_idx;
    if (tid < EE) idxb[tid] = xs_b[idx * EE + tid];
    __syncthreads();

    // ---- build scaled FX (compacted, bf16) into LDS; zero-pad to tile boundary ----
    for (int jb = 0; jb < ntp16; jb += 32) {
        int j = jb + (tid >> 3);
        int e4 = (tid & 7) * 4;
        if (j < ntp16) {
            unsigned short h0 = 0, h1 = 0, h2 = 0, h3 = 0;
            if (j < cnt) {
                int f = lst[j];
                float xv = Xrow[f];
                float4 w4 = *(const float4*)(xs_w + f * EE + e4);
                float4 b4 = *(const float4*)(xs_b + f * EE + e4);
                float4 i4 = *(const float4*)(idxb + e4);
                h0 = f2bf(SFOLD * fmaf(xv, w4.x, b4.x + i4.x));
                h1 = f2bf(SFOLD * fmaf(xv, w4.y, b4.y + i4.y));
                h2 = f2bf(SFOLD * fmaf(xv, w4.z, b4.z + i4.z));
                h3 = f2bf(SFOLD * fmaf(xv, w4.w, b4.w + i4.w));
            }
            ushort4 pk = make_ushort4(h0, h1, h2, h3);
            *(ushort4*)(fxb + j * RS + e4) = pk;
        }
    }
    __syncthreads();

    const unsigned short* myrow = fxb + (size_t)l15 * RS + grp * 8;

    // ---- pass 1: Z as column sums (E symmetric => col sum == row sum) ----
    // Padded rows are all-zero -> exp2(0)=1 per padded row; subtract pad later.
    for (int j = wv; j < nt; j += 4) {
        bf16x8 bfrag = *(const bf16x8*)(myrow + (size_t)j * 16 * RS);
        float zc0 = 0.f, zc1 = 0.f;
        const unsigned short* ap = myrow;
        int i = 0;
        for (; i + 2 <= nt; i += 2) {
            bf16x8 a0 = *(const bf16x8*)(ap);
            bf16x8 a1 = *(const bf16x8*)(ap + 16 * RS);
            ap += 32 * RS;
            f32x4 d0 = {0.f, 0.f, 0.f, 0.f};
            f32x4 d1 = {0.f, 0.f, 0.f, 0.f};
            d0 = __builtin_amdgcn_mfma_f32_16x16x32_bf16(a0, bfrag, d0, 0, 0, 0);
            d1 = __builtin_amdgcn_mfma_f32_16x16x32_bf16(a1, bfrag, d1, 0, 0, 0);
            float e00 = __builtin_amdgcn_exp2f(d0[0]);
            float e01 = __builtin_amdgcn_exp2f(d0[1]);
            float e02 = __builtin_amdgcn_exp2f(d0[2]);
            float e03 = __builtin_amdgcn_exp2f(d0[3]);
            float e10 = __builtin_amdgcn_exp2f(d1[0]);
            float e11 = __builtin_amdgcn_exp2f(d1[1]);
            float e12 = __builtin_amdgcn_exp2f(d1[2]);
            float e13 = __builtin_amdgcn_exp2f(d1[3]);
            zc0 += (e00 + e01) + (e02 + e03);
            zc1 += (e10 + e11) + (e12 + e13);
        }
        if (i < nt) {
            bf16x8 a0 = *(const bf16x8*)(ap);
            f32x4 d0 = {0.f, 0.f, 0.f, 0.f};
            d0 = __builtin_amdgcn_mfma_f32_16x16x32_bf16(a0, bfrag, d0, 0, 0, 0);
            zc0 += (__builtin_amdgcn_exp2f(d0[0]) + __builtin_amdgcn_exp2f(d0[1])) +
                   (__builtin_amdgcn_exp2f(d0[2]) + __builtin_amdgcn_exp2f(d0[3]));
        }
        float zc = zc0 + zc1;
        zc += __shfl_xor(zc, 16);
        zc += __shfl_xor(zc, 32);
        if (lane < 16) Zs[j * 16 + lane] = zc;
    }
    __syncthreads();
    {
        float pad = (float)(ntp16 - cnt);
        for (int q = tid; q < ntp16; q += 256)
            Zs[q] = (q < cnt) ? 1.f / fmaxf(Zs[q] - pad, 1e-9f) : 0.f;
    }
    __syncthreads();

    // ---- pass 2: w_k = sum_q exp(s_qk) * invZ_q (weighted column sums; invZ=0 masks) ----
    for (int j = wv; j < nt; j += 4) {
        bf16x8 bfrag = *(const bf16x8*)(myrow + (size_t)j * 16 * RS);
        float wc0 = 0.f, wc1 = 0.f;
        const unsigned short* ap = myrow;
        const float* zp = Zs + grp * 4;
        int i = 0;
        for (; i + 2 <= nt; i += 2) {
            bf16x8 a0 = *(const bf16x8*)(ap);
            bf16x8 a1 = *(const bf16x8*)(ap + 16 * RS);
            ap += 32 * RS;
            float4 z0 = *(const float4*)(zp);
            float4 z1 = *(const float4*)(zp + 16);
            zp += 32;
            f32x4 d0 = {0.f, 0.f, 0.f, 0.f};
            f32x4 d1 = {0.f, 0.f, 0.f, 0.f};
            d0 = __builtin_amdgcn_mfma_f32_16x16x32_bf16(a0, bfrag, d0, 0, 0, 0);
            d1 = __builtin_amdgcn_mfma_f32_16x16x32_bf16(a1, bfrag, d1, 0, 0, 0);
            wc0 = fmaf(__builtin_amdgcn_exp2f(d0[0]), z0.x, wc0);
            wc0 = fmaf(__builtin_amdgcn_exp2f(d0[1]), z0.y, wc0);
            wc0 = fmaf(__builtin_amdgcn_exp2f(d0[2]), z0.z, wc0);
            wc0 = fmaf(__builtin_amdgcn_exp2f(d0[3]), z0.w, wc0);
            wc1 = fmaf(__builtin_amdgcn_exp2f(d1[0]), z1.x, wc1);
            wc1 = fmaf(__builtin_amdgcn_exp2f(d1[1]), z1.y, wc1);
            wc1 = fmaf(__builtin_amdgcn_exp2f(d1[2]), z1.z, wc1);
            wc1 = fmaf(__builtin_amdgcn_exp2f(d1[3]), z1.w, wc1);
        }
        if (i < nt) {
            bf16x8 a0 = *(const bf16x8*)(ap);
            float4 z0 = *(const float4*)(zp);
            f32x4 d0 = {0.f, 0.f, 0.f, 0.f};
            d0 = __builtin_amdgcn_mfma_f32_16x16x32_bf16(a0, bfrag, d0, 0, 0, 0);
            wc0 = fmaf(__builtin_amdgcn_exp2f(d0[0]), z0.x, wc0);
            wc0 = fmaf(__builtin_amdgcn_exp2f(d0[1]), z0.y, wc0);
            wc0 = fmaf(__builtin_amdgcn_exp2f(d0[2]), z0.z, wc0);
            wc0 = fmaf(__builtin_amdgcn_exp2f(d0[3]), z0.w, wc0);
        }
        float wcs = wc0 + wc1;
        wcs += __shfl_xor(wcs, 16);
        wcs += __shfl_xor(wcs, 32);
        if (lane < 16) ws[j * 16 + lane] = wcs;
    }
    __syncthreads();

    // ---- Fxs[e] = (sum_k w_k * FX[k][e]) / cnt ; unscale by 1/SFOLD ----
    {
        int e = tid & 31, g = tid >> 5;
        float acc = 0.f;
        for (int k = g; k < cnt; k += 8)
            acc += ws[k] * bf2f(fxb[k * RS + e]);
        pf[g][e] = acc;
    }
    __syncthreads();
    if (tid < EE) {
        float s = 0.f;
#pragma unroll
        for (int g = 0; g < 8; ++g) s += pf[g][tid];
        fxs_sh[tid] = s * (1.0f / SFOLD) / (float)cnt;
    }
    __syncthreads();
    if (tid < EE) {
        float fv = fxs_sh[tid];
        pf[0][tid] = xi_w[idx * EE + tid] * fv;
    }
    __syncthreads();
    if (tid == 0) {
        float a = 0.f;
#pragma unroll
        for (int e = 0; e < EE; ++e) a += pf[0][e];
        float xiv = Xi[n];
        float mm = fmaxf(a, 0.f);
        float sp = mm + logf(__expf(a - mm) + __expf(-mm));
        out[n] = xiv * a - sp;  // xi*a - softplus(a); b-terms cancel
    }
}

extern "C" void kernel_launch(void* const* d_in, const int* in_sizes, int n_in,
                              void* d_out, int out_size, void* d_ws, size_t ws_size,
                              hipStream_t stream) {
    const float* X    = (const float*)d_in[0];
    const float* Xi   = (const float*)d_in[1];
    const float* I    = (const float*)d_in[2];
    const float* S    = (const float*)d_in[3];
    const float* xi_w = (const float*)d_in[4];
    const float* xi_b = (const float*)d_in[5];
    const float* xs_w = (const float*)d_in[6];
    const float* xs_b = (const float*)d_in[7];
    float* out = (float*)d_out;
    const int N = in_sizes[1];  // Xi is [N]
    hipLaunchKernelGGL(model_kernel, dim3(N), dim3(256), 0, stream,
                       X, Xi, I, S, xi_w, xi_b, xs_w, xs_b, out);
}

// Round 4
// 121.875 us; speedup vs baseline: 7.3491x; 1.1296x over previous
//
#include <hip/hip_runtime.h>
#include <math.h>

#define FF 512
#define EE 32
#define RS 40   // LDS row stride in bf16 elements (80 B: 2-way bank alias = free)

typedef __attribute__((ext_vector_type(8))) short bf16x8;
typedef __attribute__((ext_vector_type(4))) float f32x4;

// sqrt(1/sqrt(32) * log2(e)) — folded into staged FX so MFMA output is the exp2 arg
#define SFOLD 0.5050092f

__device__ __forceinline__ unsigned short f2bf(float x) {
    unsigned int u = __float_as_uint(x);
    return (unsigned short)((u + 0x7fffu + ((u >> 16) & 1u)) >> 16);
}
__device__ __forceinline__ float bf2f(unsigned short h) {
    return __uint_as_float(((unsigned int)h) << 16);
}

extern "C" __global__ void __launch_bounds__(512, 6)
model_kernel(const float* __restrict__ X, const float* __restrict__ Xi,
             const float* __restrict__ I, const float* __restrict__ S,
             const float* __restrict__ xi_w, const float* __restrict__ xi_b,
             const float* __restrict__ xs_w, const float* __restrict__ xs_b,
             float* __restrict__ out) {
    const int n = blockIdx.x;
    const int tid = threadIdx.x;
    const int lane = tid & 63;
    const int wv = tid >> 6;          // 8 waves per block
    const int l15 = lane & 15;
    const int grp = lane >> 4;

    __shared__ __align__(16) unsigned short fxb[FF * RS];  // 40960 B bf16 (scaled FX)
    __shared__ unsigned short lst[FF];                     // 1024 B
    __shared__ __align__(16) float Zs[FF];                 // 2048 B -> invZ
    __shared__ float ws[FF];                               // 2048 B
    __shared__ __align__(16) float idxb[EE];
    __shared__ float pf[16][EE];                           // 2048 B
    __shared__ float fxs_sh[EE];
    __shared__ int sh_idx;
    __shared__ int wbase[8];

    const float* Srow = S + (size_t)n * FF;
    const float* Irow = I + (size_t)n * FF;
    const float* Xrow = X + (size_t)n * FF;

    // one-hot index scan (512 threads cover FF exactly)
    if (Irow[tid] > 0.5f) sh_idx = tid;

    // compact active feature list (order-preserving), single round
    {
        bool act = Srow[tid] > 0.f;
        unsigned long long m = __ballot(act);
        int nb = __popcll(m & ((1ull << lane) - 1ull));
        if (lane == 0) wbase[wv] = __popcll(m);
        __syncthreads();
        int off = 0;
        for (int i = 0; i < wv; ++i) off += wbase[i];
        if (act) lst[off + nb] = (unsigned short)tid;
    }
    int cnt = 0;
#pragma unroll
    for (int i = 0; i < 8; ++i) cnt += wbase[i];
    const int nt = (cnt + 15) >> 4; // 16x16 tiles per side
    const int ntp16 = nt * 16;
    const int idx = sh_idx;
    if (tid < EE) idxb[tid] = xs_b[idx * EE + tid];
    __syncthreads();

    // ---- build scaled FX (compacted, bf16) into LDS; zero-pad to tile boundary ----
    for (int jb = 0; jb < ntp16; jb += 64) {
        int j = jb + (tid >> 3);
        int e4 = (tid & 7) * 4;
        if (j < ntp16) {
            unsigned short h0 = 0, h1 = 0, h2 = 0, h3 = 0;
            if (j < cnt) {
                int f = lst[j];
                float xv = Xrow[f];
                float4 w4 = *(const float4*)(xs_w + f * EE + e4);
                float4 b4 = *(const float4*)(xs_b + f * EE + e4);
                float4 i4 = *(const float4*)(idxb + e4);
                h0 = f2bf(SFOLD * fmaf(xv, w4.x, b4.x + i4.x));
                h1 = f2bf(SFOLD * fmaf(xv, w4.y, b4.y + i4.y));
                h2 = f2bf(SFOLD * fmaf(xv, w4.z, b4.z + i4.z));
                h3 = f2bf(SFOLD * fmaf(xv, w4.w, b4.w + i4.w));
            }
            ushort4 pk = make_ushort4(h0, h1, h2, h3);
            *(ushort4*)(fxb + j * RS + e4) = pk;
        }
    }
    __syncthreads();

    const unsigned short* myrow = fxb + (size_t)l15 * RS + grp * 8;

    // ---- pass 1: Z as column sums (score matrix symmetric => col sum == row sum) ----
    // Padded rows are all-zero -> exp2(0)=1 per padded row; subtract pad later.
    for (int j = wv; j < nt; j += 8) {
        bf16x8 bfrag = *(const bf16x8*)(myrow + (size_t)j * 16 * RS);
        float zc0 = 0.f, zc1 = 0.f;
        const unsigned short* ap = myrow;
        int i = 0;
        for (; i + 2 <= nt; i += 2) {
            bf16x8 a0 = *(const bf16x8*)(ap);
            bf16x8 a1 = *(const bf16x8*)(ap + 16 * RS);
            ap += 32 * RS;
            f32x4 d0 = {0.f, 0.f, 0.f, 0.f};
            f32x4 d1 = {0.f, 0.f, 0.f, 0.f};
            d0 = __builtin_amdgcn_mfma_f32_16x16x32_bf16(a0, bfrag, d0, 0, 0, 0);
            d1 = __builtin_amdgcn_mfma_f32_16x16x32_bf16(a1, bfrag, d1, 0, 0, 0);
            zc0 += (__builtin_amdgcn_exp2f(d0[0]) + __builtin_amdgcn_exp2f(d0[1])) +
                   (__builtin_amdgcn_exp2f(d0[2]) + __builtin_amdgcn_exp2f(d0[3]));
            zc1 += (__builtin_amdgcn_exp2f(d1[0]) + __builtin_amdgcn_exp2f(d1[1])) +
                   (__builtin_amdgcn_exp2f(d1[2]) + __builtin_amdgcn_exp2f(d1[3]));
        }
        if (i < nt) {
            bf16x8 a0 = *(const bf16x8*)(ap);
            f32x4 d0 = {0.f, 0.f, 0.f, 0.f};
            d0 = __builtin_amdgcn_mfma_f32_16x16x32_bf16(a0, bfrag, d0, 0, 0, 0);
            zc0 += (__builtin_amdgcn_exp2f(d0[0]) + __builtin_amdgcn_exp2f(d0[1])) +
                   (__builtin_amdgcn_exp2f(d0[2]) + __builtin_amdgcn_exp2f(d0[3]));
        }
        float zc = zc0 + zc1;
        zc += __shfl_xor(zc, 16);
        zc += __shfl_xor(zc, 32);
        if (lane < 16) Zs[j * 16 + lane] = zc;
    }
    __syncthreads();
    {
        float pad = (float)(ntp16 - cnt);
        for (int q = tid; q < ntp16; q += 512)
            Zs[q] = (q < cnt) ? 1.f / fmaxf(Zs[q] - pad, 1e-9f) : 0.f;
    }
    __syncthreads();

    // ---- pass 2: w_k = sum_q exp(s_qk) * invZ_q (weighted column sums; invZ=0 masks) ----
    for (int j = wv; j < nt; j += 8) {
        bf16x8 bfrag = *(const bf16x8*)(myrow + (size_t)j * 16 * RS);
        float wc0 = 0.f, wc1 = 0.f;
        const unsigned short* ap = myrow;
        const float* zp = Zs + grp * 4;
        int i = 0;
        for (; i + 2 <= nt; i += 2) {
            bf16x8 a0 = *(const bf16x8*)(ap);
            bf16x8 a1 = *(const bf16x8*)(ap + 16 * RS);
            ap += 32 * RS;
            float4 z0 = *(const float4*)(zp);
            float4 z1 = *(const float4*)(zp + 16);
            zp += 32;
            f32x4 d0 = {0.f, 0.f, 0.f, 0.f};
            f32x4 d1 = {0.f, 0.f, 0.f, 0.f};
            d0 = __builtin_amdgcn_mfma_f32_16x16x32_bf16(a0, bfrag, d0, 0, 0, 0);
            d1 = __builtin_amdgcn_mfma_f32_16x16x32_bf16(a1, bfrag, d1, 0, 0, 0);
            wc0 = fmaf(__builtin_amdgcn_exp2f(d0[0]), z0.x, wc0);
            wc0 = fmaf(__builtin_amdgcn_exp2f(d0[1]), z0.y, wc0);
            wc0 = fmaf(__builtin_amdgcn_exp2f(d0[2]), z0.z, wc0);
            wc0 = fmaf(__builtin_amdgcn_exp2f(d0[3]), z0.w, wc0);
            wc1 = fmaf(__builtin_amdgcn_exp2f(d1[0]), z1.x, wc1);
            wc1 = fmaf(__builtin_amdgcn_exp2f(d1[1]), z1.y, wc1);
            wc1 = fmaf(__builtin_amdgcn_exp2f(d1[2]), z1.z, wc1);
            wc1 = fmaf(__builtin_amdgcn_exp2f(d1[3]), z1.w, wc1);
        }
        if (i < nt) {
            bf16x8 a0 = *(const bf16x8*)(ap);
            float4 z0 = *(const float4*)(zp);
            f32x4 d0 = {0.f, 0.f, 0.f, 0.f};
            d0 = __builtin_amdgcn_mfma_f32_16x16x32_bf16(a0, bfrag, d0, 0, 0, 0);
            wc0 = fmaf(__builtin_amdgcn_exp2f(d0[0]), z0.x, wc0);
            wc0 = fmaf(__builtin_amdgcn_exp2f(d0[1]), z0.y, wc0);
            wc0 = fmaf(__builtin_amdgcn_exp2f(d0[2]), z0.z, wc0);
            wc0 = fmaf(__builtin_amdgcn_exp2f(d0[3]), z0.w, wc0);
        }
        float wcs = wc0 + wc1;
        wcs += __shfl_xor(wcs, 16);
        wcs += __shfl_xor(wcs, 32);
        if (lane < 16) ws[j * 16 + lane] = wcs;
    }
    __syncthreads();

    // ---- Fxs[e] = (sum_k w_k * FX[k][e]) / cnt ; unscale by 1/SFOLD ----
    {
        int e = tid & 31, g = tid >> 5;  // 16 groups
        float acc = 0.f;
        for (int k = g; k < cnt; k += 16)
            acc += ws[k] * bf2f(fxb[k * RS + e]);
        pf[g][e] = acc;
    }
    __syncthreads();
    if (tid < EE) {
        float s = 0.f;
#pragma unroll
        for (int g = 0; g < 16; ++g) s += pf[g][tid];
        fxs_sh[tid] = s * (1.0f / SFOLD) / (float)cnt;
    }
    __syncthreads();
    if (tid < EE) {
        float fv = fxs_sh[tid];
        pf[0][tid] = xi_w[idx * EE + tid] * fv;
    }
    __syncthreads();
    if (tid == 0) {
        float a = 0.f;
#pragma unroll
        for (int e = 0; e < EE; ++e) a += pf[0][e];
        float xiv = Xi[n];
        float mm = fmaxf(a, 0.f);
        float sp = mm + logf(__expf(a - mm) + __expf(-mm));
        out[n] = xiv * a - sp;  // xi*a - softplus(a); b-terms cancel
    }
}

extern "C" void kernel_launch(void* const* d_in, const int* in_sizes, int n_in,
                              void* d_out, int out_size, void* d_ws, size_t ws_size,
                              hipStream_t stream) {
    const float* X    = (const float*)d_in[0];
    const float* Xi   = (const float*)d_in[1];
    const float* I    = (const float*)d_in[2];
    const float* S    = (const float*)d_in[3];
    const float* xi_w = (const float*)d_in[4];
    const float* xi_b = (const float*)d_in[5];
    const float* xs_w = (const float*)d_in[6];
    const float* xs_b = (const float*)d_in[7];
    float* out = (float*)d_out;
    const int N = in_sizes[1];  // Xi is [N]
    hipLaunchKernelGGL(model_kernel, dim3(N), dim3(512), 0, stream,
                       X, Xi, I, S, xi_w, xi_b, xs_w, xs_b, out);
}